// Round 5
// baseline (599.320 us; speedup 1.0000x reference)
//
#include <hip/hip_runtime.h>
#include <hip/hip_bf16.h>

typedef __attribute__((ext_vector_type(4))) float f32x4;
typedef __attribute__((ext_vector_type(8))) short bf16x8;

#define MFMA16(a, b, c) __builtin_amdgcn_mfma_f32_16x16x32_bf16((a), (b), (c), 0, 0, 0)

// ---- LDS layout (bytes): W1 64K + W2 16K + params ~2.6K = 84512 -> 1 block/CU.
#define W1T_OFF 0        // 128 n-rows x 256 k bf16, XOR-swizzled 8-chunks
#define W2T_OFF 65536    // 64 n2-rows x 128 k bf16, fragment layout + XOR swizzle
#define B1_OFF  81920
#define G1_OFF  82432
#define E1_OFF  82944
#define B2_OFF  83456
#define G2_OFF  83712
#define E2_OFF  83968
#define W3_OFF  84224
#define B3_OFF  84480
#define SMEM_BYTES 84512

__device__ __forceinline__ short f2bf(float x) {
  __hip_bfloat16 h = __float2bfloat16(x);
  return __builtin_bit_cast(short, h);
}

__device__ __forceinline__ bf16x8 pack8(f32x4 a, f32x4 b) {
  bf16x8 r;
  r[0] = f2bf(a[0]); r[1] = f2bf(a[1]); r[2] = f2bf(a[2]); r[3] = f2bf(a[3]);
  r[4] = f2bf(b[0]); r[5] = f2bf(b[1]); r[6] = f2bf(b[2]); r[7] = f2bf(b[3]);
  return r;
}

// GELU via logistic CDF fit: Phi(z) ~= sigmoid(1.5976 z + 0.070566 z^3),
// |dgelu| <~ 5e-4 (bf16 matmul noise 0.0078 dominates; R4 passed absmax 0.0078).
__device__ __forceinline__ float gelu_fast(float z) {
  float s = z * z;
  float y = z * __builtin_fmaf(0.0705657f, s, 1.5976f);
  float t = __expf(-y);
  return z * __builtin_amdgcn_rcpf(1.0f + t);
}

// One-time weight prep into workspace (contiguous 81920 B, linear-copy stageable):
//   w1i: W1 XOR-swizzled bf16 LDS image (verified R1-R4).
//   w2i: W2 bf16 A-fragments, k-axis pi-permuted so layer-2's B operand is the
//        lane-local layer-1 accumulators (verified R2-R4), + XOR bank swizzle.
//   pi inverse: k -> q=(k>>3)&3, kb2=k>>5, e=k&7 -> n = kb2*32 + (e>>2)*16 + q*4 + (e&3)
__global__ __launch_bounds__(256) void prep_weights(
    const float* __restrict__ W1, const float* __restrict__ W2,
    short* __restrict__ w1i, short* __restrict__ w2i) {
  int idx = blockIdx.x * 256 + threadIdx.x;
  if (idx < 32768) {                       // W1 [k=256][n=128] row-major
    int k = idx >> 7, n = idx & 127;
    w1i[n * 256 + ((((k >> 3) ^ (n & 7)) << 3) | (k & 7))] = f2bf(W1[idx]);
  } else if (idx < 40960) {                // W2 [n=128][n2=64] row-major
    int j = idx - 32768;                   // j = n2*128 + pos' (swizzled fragment slot)
    int n2 = j >> 7, pos = j & 127;
    int kf = ((((pos >> 3) ^ (n2 & 7)) << 3) | (pos & 7));  // un-swizzle -> fragment k
    int q = (kf >> 3) & 3, kb2 = kf >> 5, e = kf & 7;
    int n = kb2 * 32 + (e >> 2) * 16 + q * 4 + (e & 3);     // pi inverse
    w2i[j] = f2bf(W2[n * 64 + n2]);
  }
}

// Fused gather + (256->128 LN GELU) + (128->64 LN GELU) + (64->1).
// 16 waves/block, 16 edges/wave, LDS 82.5K -> 1 block/CU, 4 waves/SIMD.
// NO 2nd launch_bounds arg: R2-R4 showed hipcc derives a 64-VGPR cap from
// (1024,4)/(1024,8) (spill catastrophe: WRITE_SIZE 170-990 MB). A bare
// 1024-thread block implies cap 128 structurally; this body peaks ~90.
// pi-trick: layer-2 B operand = layer-1 accumulators (no H1 LDS round-trip).
__global__ __launch_bounds__(1024) void mlp_fused(
    const float* __restrict__ drug, const float* __restrict__ dis,
    const int* __restrict__ src, const int* __restrict__ dst,
    const short* __restrict__ w1i,
    const float* __restrict__ b1, const float* __restrict__ g1, const float* __restrict__ be1,
    const float* __restrict__ b2, const float* __restrict__ g2, const float* __restrict__ be2,
    const float* __restrict__ W3, const float* __restrict__ b3,
    float* __restrict__ out, int E, int ntiles) {
  extern __shared__ char smem[];
  short* w1t = (short*)(smem + W1T_OFF);
  short* w2t = (short*)(smem + W2T_OFF);
  float* b1s = (float*)(smem + B1_OFF);
  float* g1s = (float*)(smem + G1_OFF);
  float* e1s = (float*)(smem + E1_OFF);
  float* b2s = (float*)(smem + B2_OFF);
  float* g2s = (float*)(smem + G2_OFF);
  float* e2s = (float*)(smem + E2_OFF);
  float* w3s = (float*)(smem + W3_OFF);
  float* b3s = (float*)(smem + B3_OFF);

  const int tid  = threadIdx.x;
  const int wave = tid >> 6;
  const int lane = tid & 63;
  const int q    = lane >> 4;   // quad (0..3)
  const int cc   = lane & 15;   // col-within-tile = edge slot

  // ---- one-time: linear copy of pre-swizzled 80KB weight image into LDS ----
  for (int o = 0; o < 5; ++o) {
    int s = (tid + o * 1024) * 8;          // shorts; 16B/thread/pass, 5 passes
    *(bf16x8*)((short*)smem + s) = *(const bf16x8*)(w1i + s);
  }
  if (tid < 128) { b1s[tid] = b1[tid]; g1s[tid] = g1[tid]; e1s[tid] = be1[tid]; }
  else if (tid < 192) { int j = tid - 128; b2s[j] = b2[j]; g2s[j] = g2[j]; e2s[j] = be2[j]; w3s[j] = W3[j]; }
  if (tid == 256) b3s[0] = b3[0];
  __syncthreads();

  // ---- persistent loop over 256-edge tiles; waves free-run (no per-tile sync) ----
  for (int tile = blockIdx.x; tile < ntiles; tile += gridDim.x) {
    const int r  = tile * 256 + wave * 16 + cc;       // this lane's edge row
    const int rc = (r < E) ? r : (E - 1);             // clamp reads, guard writes
    const float* pd = drug + (size_t)src[rc] * 128 + q * 8;
    const float* pq = dis  + (size_t)dst[rc] * 128 + q * 8;

    // ===== layer 1: [256]->[128], K=256, acc init = b1 (bias folded) =====
    f32x4 acc1[8];
    #pragma unroll
    for (int nt = 0; nt < 8; ++nt)
      acc1[nt] = *(const f32x4*)(b1s + nt * 16 + q * 4);

    f32x4 u0 = *(const f32x4*)pd;          // prefetch kb=0
    f32x4 u1 = *(const f32x4*)(pd + 4);
    #pragma unroll 1
    for (int kb = 0; kb < 8; ++kb) {
      bf16x8 bfr = pack8(u0, u1);
      if (kb < 7) {                        // issue kb+1 loads before kb's MFMAs
        const float* pn = (kb < 3) ? (pd + (kb + 1) * 32) : (pq + (kb - 3) * 32);
        u0 = *(const f32x4*)pn;
        u1 = *(const f32x4*)(pn + 4);
      }
      const char* abase = (const char*)w1t + cc * 512 + ((((kb * 4 + q) ^ (cc & 7))) << 4);
      #pragma unroll
      for (int nt = 0; nt < 8; ++nt) {
        bf16x8 af = *(const bf16x8*)(abase + nt * 8192);
        acc1[nt] = MFMA16(af, bfr, acc1[nt]);
      }
    }

    // epilogue 1: LN over n=128, GELU, pack to bf16 hreg (acc1 dies here)
    bf16x8 hreg[4];
    {
      float s = 0.f, ss = 0.f;
      #pragma unroll
      for (int nt = 0; nt < 8; ++nt)
        #pragma unroll
        for (int j = 0; j < 4; ++j) { float v = acc1[nt][j]; s += v; ss += v * v; }
      s  += __shfl_xor(s, 16);  s  += __shfl_xor(s, 32);
      ss += __shfl_xor(ss, 16); ss += __shfl_xor(ss, 32);
      float mu   = s * 0.0078125f;
      float var  = ss * 0.0078125f - mu * mu;
      var = (var > 0.f) ? var : 0.f;
      float rstd = __builtin_amdgcn_rsqf(var + 1e-5f);

      #pragma unroll
      for (int h = 0; h < 4; ++h) {
        f32x4 glo = *(const f32x4*)(g1s + (2 * h) * 16 + q * 4);
        f32x4 elo = *(const f32x4*)(e1s + (2 * h) * 16 + q * 4);
        f32x4 ghi = *(const f32x4*)(g1s + (2 * h + 1) * 16 + q * 4);
        f32x4 ehi = *(const f32x4*)(e1s + (2 * h + 1) * 16 + q * 4);
        f32x4 a, b;
        #pragma unroll
        for (int j = 0; j < 4; ++j) {
          a[j] = gelu_fast(__builtin_fmaf((acc1[2 * h][j] - mu) * rstd, glo[j], elo[j]));
          b[j] = gelu_fast(__builtin_fmaf((acc1[2 * h + 1][j] - mu) * rstd, ghi[j], ehi[j]));
        }
        hreg[h] = pack8(a, b);
      }
    }

    // ===== layer 2: [128]->[64], B operand = hreg (pi-permuted, lane-local) =====
    f32x4 acc2[4];
    #pragma unroll
    for (int t = 0; t < 4; ++t)
      acc2[t] = *(const f32x4*)(b2s + t * 16 + q * 4);

    #pragma unroll
    for (int kb2 = 0; kb2 < 4; ++kb2) {
      bf16x8 hb = hreg[kb2];
      const int ch = ((kb2 * 4 + q) ^ (cc & 7));      // swizzled chunk
      #pragma unroll
      for (int t = 0; t < 4; ++t) {
        bf16x8 af = *(const bf16x8*)(w2t + (t * 16 + cc) * 128 + ch * 8);
        acc2[t] = MFMA16(af, hb, acc2[t]);
      }
    }

    // epilogue 2: LN over n=64, GELU, dot with W3, +b3, store
    {
      float s = 0.f, ss = 0.f;
      #pragma unroll
      for (int t = 0; t < 4; ++t)
        #pragma unroll
        for (int j = 0; j < 4; ++j) { float v = acc2[t][j]; s += v; ss += v * v; }
      s  += __shfl_xor(s, 16);  s  += __shfl_xor(s, 32);
      ss += __shfl_xor(ss, 16); ss += __shfl_xor(ss, 32);
      float mu   = s * 0.015625f;
      float var  = ss * 0.015625f - mu * mu;
      var = (var > 0.f) ? var : 0.f;
      float rstd = __builtin_amdgcn_rsqf(var + 1e-5f);

      float dot = 0.f;
      #pragma unroll
      for (int t = 0; t < 4; ++t) {
        f32x4 gv = *(const f32x4*)(g2s + t * 16 + q * 4);
        f32x4 ev = *(const f32x4*)(e2s + t * 16 + q * 4);
        f32x4 wv = *(const f32x4*)(w3s + t * 16 + q * 4);
        #pragma unroll
        for (int j = 0; j < 4; ++j) {
          float zz = __builtin_fmaf((acc2[t][j] - mu) * rstd, gv[j], ev[j]);
          dot = __builtin_fmaf(gelu_fast(zz), wv[j], dot);
        }
      }
      dot += __shfl_xor(dot, 16); dot += __shfl_xor(dot, 32);
      if (q == 0 && r < E) out[r] = dot + b3s[0];
    }
  }
}

extern "C" void kernel_launch(void* const* d_in, const int* in_sizes, int n_in,
                              void* d_out, int out_size, void* d_ws, size_t ws_size,
                              hipStream_t stream) {
  const float* drug = (const float*)d_in[0];
  const float* dis  = (const float*)d_in[1];
  const int*   src  = (const int*)d_in[2];
  const int*   dst  = (const int*)d_in[3];
  const float* W1   = (const float*)d_in[4];
  const float* b1   = (const float*)d_in[5];
  const float* g1   = (const float*)d_in[6];
  const float* be1  = (const float*)d_in[7];
  const float* W2   = (const float*)d_in[8];
  const float* b2   = (const float*)d_in[9];
  const float* g2   = (const float*)d_in[10];
  const float* be2  = (const float*)d_in[11];
  const float* W3   = (const float*)d_in[12];
  const float* b3   = (const float*)d_in[13];
  float* out = (float*)d_out;

  const int E = in_sizes[2];
  const int ntiles = (E + 255) / 256;

  short* w1i = (short*)d_ws;               // 32768 shorts
  short* w2i = w1i + 32768;                // 8192 shorts (80 KB workspace total)

  (void)hipFuncSetAttribute((const void*)mlp_fused,
                            hipFuncAttributeMaxDynamicSharedMemorySize, SMEM_BYTES);

  prep_weights<<<dim3(160), dim3(256), 0, stream>>>(W1, W2, w1i, w2i);

  int grid = 256;               // persistent: 1 block/CU
  if (ntiles < grid) grid = ntiles;
  mlp_fused<<<dim3(grid), dim3(1024), SMEM_BYTES, stream>>>(
      drug, dis, src, dst, w1i, b1, g1, be1, b2, g2, be2, W3, b3, out, E, ntiles);
}

// Round 6
// 356.217 us; speedup vs baseline: 1.6825x; 1.6825x over previous
//
#include <hip/hip_runtime.h>
#include <hip/hip_bf16.h>

typedef __attribute__((ext_vector_type(4))) float f32x4;
typedef __attribute__((ext_vector_type(8))) short bf16x8;

#define MFMA16(a, b, c) __builtin_amdgcn_mfma_f32_16x16x32_bf16((a), (b), (c), 0, 0, 0)

// ---- LDS layout (bytes): W1 64K + W2 16K = 81920 = exactly 160KiB/2
// -> 2 blocks/CU at 512 threads = 16 waves/CU = 4 waves/SIMD.
// Params (b/g/be/W3/b3) read from global: tiny, L1-hot (R4 proved harmless).
#define W1T_OFF 0        // 128 n-rows x 256 k bf16, XOR-swizzled 8-chunks
#define W2T_OFF 65536    // 64 n2-rows x 128 k bf16, fragment layout + XOR swizzle
#define SMEM_BYTES 81920

__device__ __forceinline__ short f2bf(float x) {
  __hip_bfloat16 h = __float2bfloat16(x);
  return __builtin_bit_cast(short, h);
}

__device__ __forceinline__ bf16x8 pack8(f32x4 a, f32x4 b) {
  bf16x8 r;
  r[0] = f2bf(a[0]); r[1] = f2bf(a[1]); r[2] = f2bf(a[2]); r[3] = f2bf(a[3]);
  r[4] = f2bf(b[0]); r[5] = f2bf(b[1]); r[6] = f2bf(b[2]); r[7] = f2bf(b[3]);
  return r;
}

// GELU via logistic CDF fit: Phi(z) ~= sigmoid(1.5976 z + 0.070566 z^3),
// |dgelu| <~ 5e-4 (bf16 matmul noise 0.0078 dominates; R4/R5 passed absmax 0.0078).
__device__ __forceinline__ float gelu_fast(float z) {
  float s = z * z;
  float y = z * __builtin_fmaf(0.0705657f, s, 1.5976f);
  float t = __expf(-y);
  return z * __builtin_amdgcn_rcpf(1.0f + t);
}

// One-time weight prep into workspace (contiguous 81920 B, linear-copy stageable):
//   w1i: W1 XOR-swizzled bf16 LDS image (verified R1-R5).
//   w2i: W2 bf16 A-fragments, k-axis pi-permuted so layer-2's B operand is the
//        lane-local layer-1 accumulators (verified R2-R5), + XOR bank swizzle.
//   pi inverse: k -> q=(k>>3)&3, kb2=k>>5, e=k&7 -> n = kb2*32 + (e>>2)*16 + q*4 + (e&3)
__global__ __launch_bounds__(256) void prep_weights(
    const float* __restrict__ W1, const float* __restrict__ W2,
    short* __restrict__ w1i, short* __restrict__ w2i) {
  int idx = blockIdx.x * 256 + threadIdx.x;
  if (idx < 32768) {                       // W1 [k=256][n=128] row-major
    int k = idx >> 7, n = idx & 127;
    w1i[n * 256 + ((((k >> 3) ^ (n & 7)) << 3) | (k & 7))] = f2bf(W1[idx]);
  } else if (idx < 40960) {                // W2 [n=128][n2=64] row-major
    int j = idx - 32768;                   // j = n2*128 + pos' (swizzled fragment slot)
    int n2 = j >> 7, pos = j & 127;
    int kf = ((((pos >> 3) ^ (n2 & 7)) << 3) | (pos & 7));  // un-swizzle -> fragment k
    int q = (kf >> 3) & 3, kb2 = kf >> 5, e = kf & 7;
    int n = kb2 * 32 + (e >> 2) * 16 + q * 4 + (e & 3);     // pi inverse
    w2i[j] = f2bf(W2[n * 64 + n2]);
  }
}

// Fused gather + (256->128 LN GELU) + (128->64 LN GELU) + (64->1).
// 8 waves/block (512 thr), 16 edges/wave, 128-edge tiles.
// VGPR-budget lesson (R2-R5): hipcc gives 1024-thread blocks a 64-VGPR budget
// (unconditional spill for this ~90-reg body). 512-thr + (512,2) is the proven
// >=128-reg configuration (R0: 84 regs, no spill). Occupancy comes from
// 2 blocks/CU (LDS exactly 80 KiB) instead of a bigger block.
// pi-trick: layer-2 B operand = layer-1 accumulators (no H1 LDS round-trip).
__global__ __launch_bounds__(512, 2) void mlp_fused(
    const float* __restrict__ drug, const float* __restrict__ dis,
    const int* __restrict__ src, const int* __restrict__ dst,
    const short* __restrict__ w1i,
    const float* __restrict__ b1, const float* __restrict__ g1, const float* __restrict__ be1,
    const float* __restrict__ b2, const float* __restrict__ g2, const float* __restrict__ be2,
    const float* __restrict__ W3, const float* __restrict__ b3,
    float* __restrict__ out, int E, int ntiles) {
  extern __shared__ char smem[];
  short* w1t = (short*)(smem + W1T_OFF);
  short* w2t = (short*)(smem + W2T_OFF);

  const int tid  = threadIdx.x;
  const int wave = tid >> 6;    // 0..7
  const int lane = tid & 63;
  const int q    = lane >> 4;   // quad (0..3)
  const int cc   = lane & 15;   // col-within-tile = edge slot

  // ---- one-time: linear copy of pre-swizzled 80KB weight image into LDS ----
  #pragma unroll
  for (int o = 0; o < 10; ++o) {
    int s = (tid + o * 512) * 8;           // shorts; 16B/thread/pass, 10 passes
    *(bf16x8*)((short*)smem + s) = *(const bf16x8*)(w1i + s);
  }
  __syncthreads();

  const float bias3 = b3[0];               // uniform -> scalar

  // ---- persistent loop over 128-edge tiles; waves free-run (no per-tile sync) ----
  for (int tile = blockIdx.x; tile < ntiles; tile += gridDim.x) {
    const int r  = tile * 128 + wave * 16 + cc;       // this lane's edge row
    const int rc = (r < E) ? r : (E - 1);             // clamp reads, guard writes
    const float* pd = drug + (size_t)src[rc] * 128 + q * 8;
    const float* pq = dis  + (size_t)dst[rc] * 128 + q * 8;

    // ===== layer 1: [256]->[128], K=256, acc init = b1 (bias folded) =====
    f32x4 acc1[8];
    #pragma unroll
    for (int nt = 0; nt < 8; ++nt)
      acc1[nt] = *(const f32x4*)(b1 + nt * 16 + q * 4);

    f32x4 u0 = *(const f32x4*)pd;          // prefetch kb=0
    f32x4 u1 = *(const f32x4*)(pd + 4);
    #pragma unroll 1
    for (int kb = 0; kb < 8; ++kb) {
      bf16x8 bfr = pack8(u0, u1);
      if (kb < 7) {                        // issue kb+1 loads before kb's MFMAs
        const float* pn = (kb < 3) ? (pd + (kb + 1) * 32) : (pq + (kb - 3) * 32);
        u0 = *(const f32x4*)pn;
        u1 = *(const f32x4*)(pn + 4);
      }
      const char* abase = (const char*)w1t + cc * 512 + ((((kb * 4 + q) ^ (cc & 7))) << 4);
      #pragma unroll
      for (int nt = 0; nt < 8; ++nt) {
        bf16x8 af = *(const bf16x8*)(abase + nt * 8192);
        acc1[nt] = MFMA16(af, bfr, acc1[nt]);
      }
    }

    // epilogue 1: LN over n=128, GELU, pack to bf16 hreg (acc1 dies here)
    bf16x8 hreg[4];
    {
      float s = 0.f, ss = 0.f;
      #pragma unroll
      for (int nt = 0; nt < 8; ++nt)
        #pragma unroll
        for (int j = 0; j < 4; ++j) { float v = acc1[nt][j]; s += v; ss += v * v; }
      s  += __shfl_xor(s, 16);  s  += __shfl_xor(s, 32);
      ss += __shfl_xor(ss, 16); ss += __shfl_xor(ss, 32);
      float mu   = s * 0.0078125f;
      float var  = ss * 0.0078125f - mu * mu;
      var = (var > 0.f) ? var : 0.f;
      float rstd = __builtin_amdgcn_rsqf(var + 1e-5f);

      #pragma unroll
      for (int h = 0; h < 4; ++h) {
        f32x4 glo = *(const f32x4*)(g1  + (2 * h) * 16 + q * 4);
        f32x4 elo = *(const f32x4*)(be1 + (2 * h) * 16 + q * 4);
        f32x4 ghi = *(const f32x4*)(g1  + (2 * h + 1) * 16 + q * 4);
        f32x4 ehi = *(const f32x4*)(be1 + (2 * h + 1) * 16 + q * 4);
        f32x4 a, b;
        #pragma unroll
        for (int j = 0; j < 4; ++j) {
          a[j] = gelu_fast(__builtin_fmaf((acc1[2 * h][j] - mu) * rstd, glo[j], elo[j]));
          b[j] = gelu_fast(__builtin_fmaf((acc1[2 * h + 1][j] - mu) * rstd, ghi[j], ehi[j]));
        }
        hreg[h] = pack8(a, b);
      }
    }

    // ===== layer 2: [128]->[64], B operand = hreg (pi-permuted, lane-local) =====
    f32x4 acc2[4];
    #pragma unroll
    for (int t = 0; t < 4; ++t)
      acc2[t] = *(const f32x4*)(b2 + t * 16 + q * 4);

    #pragma unroll
    for (int kb2 = 0; kb2 < 4; ++kb2) {
      bf16x8 hb = hreg[kb2];
      const int ch = ((kb2 * 4 + q) ^ (cc & 7));      // swizzled chunk
      #pragma unroll
      for (int t = 0; t < 4; ++t) {
        bf16x8 af = *(const bf16x8*)(w2t + (t * 16 + cc) * 128 + ch * 8);
        acc2[t] = MFMA16(af, hb, acc2[t]);
      }
    }

    // epilogue 2: LN over n=64, GELU, dot with W3, +b3, store
    {
      float s = 0.f, ss = 0.f;
      #pragma unroll
      for (int t = 0; t < 4; ++t)
        #pragma unroll
        for (int j = 0; j < 4; ++j) { float v = acc2[t][j]; s += v; ss += v * v; }
      s  += __shfl_xor(s, 16);  s  += __shfl_xor(s, 32);
      ss += __shfl_xor(ss, 16); ss += __shfl_xor(ss, 32);
      float mu   = s * 0.015625f;
      float var  = ss * 0.015625f - mu * mu;
      var = (var > 0.f) ? var : 0.f;
      float rstd = __builtin_amdgcn_rsqf(var + 1e-5f);

      float dot = 0.f;
      #pragma unroll
      for (int t = 0; t < 4; ++t) {
        f32x4 gv = *(const f32x4*)(g2  + t * 16 + q * 4);
        f32x4 ev = *(const f32x4*)(be2 + t * 16 + q * 4);
        f32x4 wv = *(const f32x4*)(W3  + t * 16 + q * 4);
        #pragma unroll
        for (int j = 0; j < 4; ++j) {
          float zz = __builtin_fmaf((acc2[t][j] - mu) * rstd, gv[j], ev[j]);
          dot = __builtin_fmaf(gelu_fast(zz), wv[j], dot);
        }
      }
      dot += __shfl_xor(dot, 16); dot += __shfl_xor(dot, 32);
      if (q == 0 && r < E) out[r] = dot + bias3;
    }
  }
}

extern "C" void kernel_launch(void* const* d_in, const int* in_sizes, int n_in,
                              void* d_out, int out_size, void* d_ws, size_t ws_size,
                              hipStream_t stream) {
  const float* drug = (const float*)d_in[0];
  const float* dis  = (const float*)d_in[1];
  const int*   src  = (const int*)d_in[2];
  const int*   dst  = (const int*)d_in[3];
  const float* W1   = (const float*)d_in[4];
  const float* b1   = (const float*)d_in[5];
  const float* g1   = (const float*)d_in[6];
  const float* be1  = (const float*)d_in[7];
  const float* W2   = (const float*)d_in[8];
  const float* b2   = (const float*)d_in[9];
  const float* g2   = (const float*)d_in[10];
  const float* be2  = (const float*)d_in[11];
  const float* W3   = (const float*)d_in[12];
  const float* b3   = (const float*)d_in[13];
  float* out = (float*)d_out;

  const int E = in_sizes[2];
  const int ntiles = (E + 127) / 128;      // 128-edge tiles (8 waves x 16 edges)

  short* w1i = (short*)d_ws;               // 32768 shorts
  short* w2i = w1i + 32768;                // 8192 shorts (80 KB workspace total)

  (void)hipFuncSetAttribute((const void*)mlp_fused,
                            hipFuncAttributeMaxDynamicSharedMemorySize, SMEM_BYTES);

  prep_weights<<<dim3(160), dim3(256), 0, stream>>>(W1, W2, w1i, w2i);

  int grid = 512;               // persistent: 2 blocks/CU (LDS exactly 80 KiB)
  if (ntiles < grid) grid = ntiles;
  mlp_fused<<<dim3(grid), dim3(512), SMEM_BYTES, stream>>>(
      drug, dis, src, dst, w1i, b1, g1, be1, b2, g2, be2, W3, b3, out, E, ntiles);
}

// Round 7
// 276.194 us; speedup vs baseline: 2.1699x; 1.2897x over previous
//
#include <hip/hip_runtime.h>
#include <hip/hip_bf16.h>

typedef __attribute__((ext_vector_type(4))) float f32x4;
typedef __attribute__((ext_vector_type(8))) short bf16x8;

#define MFMA16(a, b, c) __builtin_amdgcn_mfma_f32_16x16x32_bf16((a), (b), (c), 0, 0, 0)

// ---- LDS layout (bytes): W1 64K + params ~2.6K = 68128.
// 2 blocks/CU = 136 KB < 160 KiB with 27 KB margin (R6 lesson: the exact
// 2x80 KiB fit failed residency -> only 1 block/CU; never pack to the boundary).
// W2 (16 KB) reads from global per tile: L1/L2-hot.
#define W1T_OFF 0        // 128 n-rows x 256 k bf16, XOR-swizzled 8-chunks
#define B1_OFF  65536
#define G1_OFF  66048
#define E1_OFF  66560
#define B2_OFF  67072
#define G2_OFF  67328
#define E2_OFF  67584
#define W3_OFF  67840
#define B3_OFF  68096
#define SMEM_BYTES 68128

__device__ __forceinline__ short f2bf(float x) {
  __hip_bfloat16 h = __float2bfloat16(x);
  return __builtin_bit_cast(short, h);
}

__device__ __forceinline__ bf16x8 pack8(f32x4 a, f32x4 b) {
  bf16x8 r;
  r[0] = f2bf(a[0]); r[1] = f2bf(a[1]); r[2] = f2bf(a[2]); r[3] = f2bf(a[3]);
  r[4] = f2bf(b[0]); r[5] = f2bf(b[1]); r[6] = f2bf(b[2]); r[7] = f2bf(b[3]);
  return r;
}

// GELU via logistic CDF fit: Phi(z) ~= sigmoid(1.5976 z + 0.070566 z^3),
// |dgelu| <~ 5e-4 (bf16 matmul noise 0.0078 dominates; R4-R6 passed absmax 0.0078).
__device__ __forceinline__ float gelu_fast(float z) {
  float s = z * z;
  float y = z * __builtin_fmaf(0.0705657f, s, 1.5976f);
  float t = __expf(-y);
  return z * __builtin_amdgcn_rcpf(1.0f + t);
}

// One-time weight prep into workspace:
//   w1i: W1 XOR-swizzled bf16 LDS image (verified R1-R6).
//   w2i: W2 bf16 A-fragments, k-axis pi-permuted so layer-2's B operand is the
//        lane-local layer-1 accumulators (verified R2-R6), + XOR chunk swizzle
//        (harmless now that w2i is read from global; prep kept identical).
//   pi inverse: k -> q=(k>>3)&3, kb2=k>>5, e=k&7 -> n = kb2*32 + (e>>2)*16 + q*4 + (e&3)
__global__ __launch_bounds__(256) void prep_weights(
    const float* __restrict__ W1, const float* __restrict__ W2,
    short* __restrict__ w1i, short* __restrict__ w2i) {
  int idx = blockIdx.x * 256 + threadIdx.x;
  if (idx < 32768) {                       // W1 [k=256][n=128] row-major
    int k = idx >> 7, n = idx & 127;
    w1i[n * 256 + ((((k >> 3) ^ (n & 7)) << 3) | (k & 7))] = f2bf(W1[idx]);
  } else if (idx < 40960) {                // W2 [n=128][n2=64] row-major
    int j = idx - 32768;                   // j = n2*128 + pos' (swizzled fragment slot)
    int n2 = j >> 7, pos = j & 127;
    int kf = ((((pos >> 3) ^ (n2 & 7)) << 3) | (pos & 7));  // un-swizzle -> fragment k
    int q = (kf >> 3) & 3, kb2 = kf >> 5, e = kf & 7;
    int n = kb2 * 32 + (e >> 2) * 16 + q * 4 + (e & 3);     // pi inverse
    w2i[j] = f2bf(W2[n * 64 + n2]);
  }
}

// Fused gather + (256->128 LN GELU) + (128->64 LN GELU) + (64->1).
// 8 waves/block (512 thr), 16 edges/wave, 128-edge tiles, 2 blocks/CU.
// Register-pressure lessons (R2-R6):
//  - 1024-thr blocks get a hard 64-VGPR budget from hipcc -> unusable for this body.
//  - global param loads in the epilogue get batch-hoisted (+64 regs) -> params
//    live in LDS (ds_reads, quad-uniform broadcast).
//  - W2-from-global fragment loads fenced per kb2 with sched_barrier(0) to cap
//    in-flight loads at 4 (16 regs) instead of 16 (64 regs).
// pi-trick: layer-2 B operand = layer-1 accumulators (no H1 LDS round-trip).
__global__ __launch_bounds__(512, 2) void mlp_fused(
    const float* __restrict__ drug, const float* __restrict__ dis,
    const int* __restrict__ src, const int* __restrict__ dst,
    const short* __restrict__ w1i, const short* __restrict__ w2i,
    const float* __restrict__ b1, const float* __restrict__ g1, const float* __restrict__ be1,
    const float* __restrict__ b2, const float* __restrict__ g2, const float* __restrict__ be2,
    const float* __restrict__ W3, const float* __restrict__ b3,
    float* __restrict__ out, int E, int ntiles) {
  extern __shared__ char smem[];
  short* w1t = (short*)(smem + W1T_OFF);
  float* b1s = (float*)(smem + B1_OFF);
  float* g1s = (float*)(smem + G1_OFF);
  float* e1s = (float*)(smem + E1_OFF);
  float* b2s = (float*)(smem + B2_OFF);
  float* g2s = (float*)(smem + G2_OFF);
  float* e2s = (float*)(smem + E2_OFF);
  float* w3s = (float*)(smem + W3_OFF);
  float* b3s = (float*)(smem + B3_OFF);

  const int tid  = threadIdx.x;
  const int wave = tid >> 6;    // 0..7
  const int lane = tid & 63;
  const int q    = lane >> 4;   // quad (0..3)
  const int cc   = lane & 15;   // col-within-tile = edge slot

  // ---- one-time: linear copy of pre-swizzled 64KB W1 image into LDS ----
  #pragma unroll
  for (int o = 0; o < 8; ++o) {
    int s = (tid + o * 512) * 8;           // shorts; 16B/thread/pass, 8 passes
    *(bf16x8*)(w1t + s) = *(const bf16x8*)(w1i + s);
  }
  if (tid < 128) { b1s[tid] = b1[tid]; g1s[tid] = g1[tid]; e1s[tid] = be1[tid]; }
  else if (tid < 192) { int j = tid - 128; b2s[j] = b2[j]; g2s[j] = g2[j]; e2s[j] = be2[j]; w3s[j] = W3[j]; }
  if (tid == 256) b3s[0] = b3[0];
  __syncthreads();

  // per-lane W2 fragment base (global, L1-hot): fragment(t,kb2) at
  // w2p + t*16*128 + ch*8 where ch = (kb2*4+q)^(cc&7)
  const short* w2p = w2i + cc * 128;

  // ---- persistent loop over 128-edge tiles; waves free-run (no per-tile sync) ----
  for (int tile = blockIdx.x; tile < ntiles; tile += gridDim.x) {
    const int r  = tile * 128 + wave * 16 + cc;       // this lane's edge row
    const int rc = (r < E) ? r : (E - 1);             // clamp reads, guard writes
    const float* pd = drug + (size_t)src[rc] * 128 + q * 8;
    const float* pq = dis  + (size_t)dst[rc] * 128 + q * 8;

    // ===== layer 1: [256]->[128], K=256, acc init = b1 (bias folded) =====
    f32x4 acc1[8];
    #pragma unroll
    for (int nt = 0; nt < 8; ++nt)
      acc1[nt] = *(const f32x4*)(b1s + nt * 16 + q * 4);

    f32x4 u0 = *(const f32x4*)pd;          // prefetch kb=0
    f32x4 u1 = *(const f32x4*)(pd + 4);
    #pragma unroll 1
    for (int kb = 0; kb < 8; ++kb) {
      bf16x8 bfr = pack8(u0, u1);
      if (kb < 7) {                        // issue kb+1 loads before kb's MFMAs
        const float* pn = (kb < 3) ? (pd + (kb + 1) * 32) : (pq + (kb - 3) * 32);
        u0 = *(const f32x4*)pn;
        u1 = *(const f32x4*)(pn + 4);
      }
      const char* abase = (const char*)w1t + cc * 512 + ((((kb * 4 + q) ^ (cc & 7))) << 4);
      #pragma unroll
      for (int nt = 0; nt < 8; ++nt) {
        bf16x8 af = *(const bf16x8*)(abase + nt * 8192);
        acc1[nt] = MFMA16(af, bfr, acc1[nt]);
      }
    }

    // epilogue 1: LN over n=128, GELU, pack to bf16 hreg (acc1 dies here)
    bf16x8 hreg[4];
    {
      float s = 0.f, ss = 0.f;
      #pragma unroll
      for (int nt = 0; nt < 8; ++nt)
        #pragma unroll
        for (int j = 0; j < 4; ++j) { float v = acc1[nt][j]; s += v; ss += v * v; }
      s  += __shfl_xor(s, 16);  s  += __shfl_xor(s, 32);
      ss += __shfl_xor(ss, 16); ss += __shfl_xor(ss, 32);
      float mu   = s * 0.0078125f;
      float var  = ss * 0.0078125f - mu * mu;
      var = (var > 0.f) ? var : 0.f;
      float rstd = __builtin_amdgcn_rsqf(var + 1e-5f);

      #pragma unroll
      for (int h = 0; h < 4; ++h) {
        f32x4 glo = *(const f32x4*)(g1s + (2 * h) * 16 + q * 4);
        f32x4 elo = *(const f32x4*)(e1s + (2 * h) * 16 + q * 4);
        f32x4 ghi = *(const f32x4*)(g1s + (2 * h + 1) * 16 + q * 4);
        f32x4 ehi = *(const f32x4*)(e1s + (2 * h + 1) * 16 + q * 4);
        f32x4 a, b;
        #pragma unroll
        for (int j = 0; j < 4; ++j) {
          a[j] = gelu_fast(__builtin_fmaf((acc1[2 * h][j] - mu) * rstd, glo[j], elo[j]));
          b[j] = gelu_fast(__builtin_fmaf((acc1[2 * h + 1][j] - mu) * rstd, ghi[j], ehi[j]));
        }
        hreg[h] = pack8(a, b);
      }
    }

    // ===== layer 2: [128]->[64], B operand = hreg (pi-permuted, lane-local),
    // A fragments streamed from global (L1-hot), fenced to cap reg pressure =====
    f32x4 acc2[4];
    #pragma unroll
    for (int t = 0; t < 4; ++t)
      acc2[t] = *(const f32x4*)(b2s + t * 16 + q * 4);

    #pragma unroll
    for (int kb2 = 0; kb2 < 4; ++kb2) {
      bf16x8 hb = hreg[kb2];
      const int ch = ((kb2 * 4 + q) ^ (cc & 7));      // swizzled chunk
      #pragma unroll
      for (int t = 0; t < 4; ++t) {
        bf16x8 af = *(const bf16x8*)(w2p + t * 2048 + ch * 8);
        acc2[t] = MFMA16(af, hb, acc2[t]);
      }
      __builtin_amdgcn_sched_barrier(0);   // cap in-flight W2 loads at 4 (16 regs)
    }

    // epilogue 2: LN over n=64, GELU, dot with W3, +b3, store
    {
      float s = 0.f, ss = 0.f;
      #pragma unroll
      for (int t = 0; t < 4; ++t)
        #pragma unroll
        for (int j = 0; j < 4; ++j) { float v = acc2[t][j]; s += v; ss += v * v; }
      s  += __shfl_xor(s, 16);  s  += __shfl_xor(s, 32);
      ss += __shfl_xor(ss, 16); ss += __shfl_xor(ss, 32);
      float mu   = s * 0.015625f;
      float var  = ss * 0.015625f - mu * mu;
      var = (var > 0.f) ? var : 0.f;
      float rstd = __builtin_amdgcn_rsqf(var + 1e-5f);

      float dot = 0.f;
      #pragma unroll
      for (int t = 0; t < 4; ++t) {
        f32x4 gv = *(const f32x4*)(g2s + t * 16 + q * 4);
        f32x4 ev = *(const f32x4*)(e2s + t * 16 + q * 4);
        f32x4 wv = *(const f32x4*)(w3s + t * 16 + q * 4);
        #pragma unroll
        for (int j = 0; j < 4; ++j) {
          float zz = __builtin_fmaf((acc2[t][j] - mu) * rstd, gv[j], ev[j]);
          dot = __builtin_fmaf(gelu_fast(zz), wv[j], dot);
        }
      }
      dot += __shfl_xor(dot, 16); dot += __shfl_xor(dot, 32);
      if (q == 0 && r < E) out[r] = dot + b3s[0];
    }
  }
}

extern "C" void kernel_launch(void* const* d_in, const int* in_sizes, int n_in,
                              void* d_out, int out_size, void* d_ws, size_t ws_size,
                              hipStream_t stream) {
  const float* drug = (const float*)d_in[0];
  const float* dis  = (const float*)d_in[1];
  const int*   src  = (const int*)d_in[2];
  const int*   dst  = (const int*)d_in[3];
  const float* W1   = (const float*)d_in[4];
  const float* b1   = (const float*)d_in[5];
  const float* g1   = (const float*)d_in[6];
  const float* be1  = (const float*)d_in[7];
  const float* W2   = (const float*)d_in[8];
  const float* b2   = (const float*)d_in[9];
  const float* g2   = (const float*)d_in[10];
  const float* be2  = (const float*)d_in[11];
  const float* W3   = (const float*)d_in[12];
  const float* b3   = (const float*)d_in[13];
  float* out = (float*)d_out;

  const int E = in_sizes[2];
  const int ntiles = (E + 127) / 128;      // 128-edge tiles (8 waves x 16 edges)

  short* w1i = (short*)d_ws;               // 32768 shorts
  short* w2i = w1i + 32768;                // 8192 shorts (80 KB workspace total)

  (void)hipFuncSetAttribute((const void*)mlp_fused,
                            hipFuncAttributeMaxDynamicSharedMemorySize, SMEM_BYTES);

  prep_weights<<<dim3(160), dim3(256), 0, stream>>>(W1, W2, w1i, w2i);

  int grid = 512;               // persistent: 2 blocks/CU (LDS 66.5K + margin)
  if (ntiles < grid) grid = ntiles;
  mlp_fused<<<dim3(grid), dim3(512), SMEM_BYTES, stream>>>(
      drug, dis, src, dst, w1i, w2i, b1, g1, be1, b2, g2, be2, W3, b3, out, E, ntiles);
}

// Round 8
// 251.020 us; speedup vs baseline: 2.3875x; 1.1003x over previous
//
#include <hip/hip_runtime.h>
#include <hip/hip_bf16.h>

typedef __attribute__((ext_vector_type(4))) float f32x4;
typedef __attribute__((ext_vector_type(8))) short bf16x8;

#define MFMA16(a, b, c) __builtin_amdgcn_mfma_f32_16x16x32_bf16((a), (b), (c), 0, 0, 0)

// ---- LDS layout (bytes): W1 64K + params ~2.6K = 68128 (R7-proven geometry).
// W2 (16 KB) reads from global per tile: L1/L2-hot, fenced (R7-proven).
#define W1T_OFF 0        // 128 n-rows x 256 k bf16, XOR-swizzled 8-chunks
#define B1_OFF  65536
#define G1_OFF  66048
#define E1_OFF  66560
#define B2_OFF  67072
#define G2_OFF  67328
#define E2_OFF  67584
#define W3_OFF  67840
#define B3_OFF  68096
#define SMEM_BYTES 68128

__device__ __forceinline__ short f2bf(float x) {
  __hip_bfloat16 h = __float2bfloat16(x);
  return __builtin_bit_cast(short, h);
}

__device__ __forceinline__ bf16x8 pack8(f32x4 a, f32x4 b) {
  bf16x8 r;
  r[0] = f2bf(a[0]); r[1] = f2bf(a[1]); r[2] = f2bf(a[2]); r[3] = f2bf(a[3]);
  r[4] = f2bf(b[0]); r[5] = f2bf(b[1]); r[6] = f2bf(b[2]); r[7] = f2bf(b[3]);
  return r;
}

// GELU via logistic CDF fit: Phi(z) ~= sigmoid(1.5976 z + 0.070566 z^3),
// |dgelu| <~ 5e-4 (bf16 matmul noise 0.0078 dominates; R4-R7 passed absmax 0.0078).
__device__ __forceinline__ float gelu_fast(float z) {
  float s = z * z;
  float y = z * __builtin_fmaf(0.0705657f, s, 1.5976f);
  float t = __expf(-y);
  return z * __builtin_amdgcn_rcpf(1.0f + t);
}

// One-time weight prep into workspace:
//   w1i: W1 XOR-swizzled bf16 LDS image (verified R1-R7).
//   w2i: W2 bf16 A-fragments, k-axis pi-permuted so layer-2's B operand is the
//        lane-local layer-1 accumulators (verified R2-R7), + XOR chunk swizzle.
//   pi inverse: k -> q=(k>>3)&3, kb2=k>>5, e=k&7 -> n = kb2*32 + (e>>2)*16 + q*4 + (e&3)
__global__ __launch_bounds__(256) void prep_weights(
    const float* __restrict__ W1, const float* __restrict__ W2,
    short* __restrict__ w1i, short* __restrict__ w2i) {
  int idx = blockIdx.x * 256 + threadIdx.x;
  if (idx < 32768) {                       // W1 [k=256][n=128] row-major
    int k = idx >> 7, n = idx & 127;
    w1i[n * 256 + ((((k >> 3) ^ (n & 7)) << 3) | (k & 7))] = f2bf(W1[idx]);
  } else if (idx < 40960) {                // W2 [n=128][n2=64] row-major
    int j = idx - 32768;                   // j = n2*128 + pos' (swizzled fragment slot)
    int n2 = j >> 7, pos = j & 127;
    int kf = ((((pos >> 3) ^ (n2 & 7)) << 3) | (pos & 7));  // un-swizzle -> fragment k
    int q = (kf >> 3) & 3, kb2 = kf >> 5, e = kf & 7;
    int n = kb2 * 32 + (e >> 2) * 16 + q * 4 + (e & 3);     // pi inverse
    w2i[j] = f2bf(W2[n * 64 + n2]);
  }
}

// One-time feature-table conversion f32 -> bf16 (halves gather bytes; kills
// the in-loop f32->bf16 pack; 5.1 MB total sits mostly in L2).
__global__ __launch_bounds__(256) void prep_feats(
    const float* __restrict__ f, short* __restrict__ o, int n8) {
  int idx = blockIdx.x * 256 + threadIdx.x;
  if (idx < n8) {
    f32x4 a = *(const f32x4*)(f + idx * 8);
    f32x4 b = *(const f32x4*)(f + idx * 8 + 4);
    *(bf16x8*)(o + idx * 8) = pack8(a, b);
  }
}

// Fused gather + (256->128 LN GELU) + (128->64 LN GELU) + (64->1).
// 8 waves/block (512 thr), 16 edges/wave, 128-edge tiles.
// Geometry/register lessons (R2-R7, all counter-verified):
//  - (512,2) is the proven 128-reg-budget config (76 regs, zero scratch).
//  - 1024-thr blocks get a 64-reg budget from hipcc -> unconditional spill.
//  - params in LDS (global param loads get batch-hoisted: +64 regs, spill).
//  - W2-from-global fenced per kb2 with sched_barrier(0) caps in-flight loads.
//  - 512-thr blocks do NOT co-reside 2/CU despite fitting resources (R6/R7
//    measured ~22% = 8 waves/CU); cause unknown -- do not re-spend on it blind.
// pi-trick: layer-2 B operand = layer-1 accumulators (no H1 LDS round-trip).
// Gathers read pre-converted bf16 tables (this round's change).
__global__ __launch_bounds__(512, 2) void mlp_fused(
    const short* __restrict__ drugb, const short* __restrict__ disb,
    const int* __restrict__ src, const int* __restrict__ dst,
    const short* __restrict__ w1i, const short* __restrict__ w2i,
    const float* __restrict__ b1, const float* __restrict__ g1, const float* __restrict__ be1,
    const float* __restrict__ b2, const float* __restrict__ g2, const float* __restrict__ be2,
    const float* __restrict__ W3, const float* __restrict__ b3,
    float* __restrict__ out, int E, int ntiles) {
  extern __shared__ char smem[];
  short* w1t = (short*)(smem + W1T_OFF);
  float* b1s = (float*)(smem + B1_OFF);
  float* g1s = (float*)(smem + G1_OFF);
  float* e1s = (float*)(smem + E1_OFF);
  float* b2s = (float*)(smem + B2_OFF);
  float* g2s = (float*)(smem + G2_OFF);
  float* e2s = (float*)(smem + E2_OFF);
  float* w3s = (float*)(smem + W3_OFF);
  float* b3s = (float*)(smem + B3_OFF);

  const int tid  = threadIdx.x;
  const int wave = tid >> 6;    // 0..7
  const int lane = tid & 63;
  const int q    = lane >> 4;   // quad (0..3)
  const int cc   = lane & 15;   // col-within-tile = edge slot

  // ---- one-time: linear copy of pre-swizzled 64KB W1 image into LDS ----
  #pragma unroll
  for (int o = 0; o < 8; ++o) {
    int s = (tid + o * 512) * 8;           // shorts; 16B/thread/pass, 8 passes
    *(bf16x8*)(w1t + s) = *(const bf16x8*)(w1i + s);
  }
  if (tid < 128) { b1s[tid] = b1[tid]; g1s[tid] = g1[tid]; e1s[tid] = be1[tid]; }
  else if (tid < 192) { int j = tid - 128; b2s[j] = b2[j]; g2s[j] = g2[j]; e2s[j] = be2[j]; w3s[j] = W3[j]; }
  if (tid == 256) b3s[0] = b3[0];
  __syncthreads();

  // per-lane W2 fragment base (global, L1-hot)
  const short* w2p = w2i + cc * 128;

  // ---- persistent loop over 128-edge tiles; waves free-run (no per-tile sync) ----
  for (int tile = blockIdx.x; tile < ntiles; tile += gridDim.x) {
    const int r  = tile * 128 + wave * 16 + cc;       // this lane's edge row
    const int rc = (r < E) ? r : (E - 1);             // clamp reads, guard writes
    const short* pd = drugb + (size_t)src[rc] * 128 + q * 8;
    const short* pq = disb  + (size_t)dst[rc] * 128 + q * 8;

    // ===== layer 1: [256]->[128], K=256, acc init = b1 (bias folded) =====
    f32x4 acc1[8];
    #pragma unroll
    for (int nt = 0; nt < 8; ++nt)
      acc1[nt] = *(const f32x4*)(b1s + nt * 16 + q * 4);

    bf16x8 u = *(const bf16x8*)pd;         // prefetch kb=0 (bf16 direct!)
    #pragma unroll 1
    for (int kb = 0; kb < 8; ++kb) {
      bf16x8 bfr = u;
      if (kb < 7) {                        // issue kb+1 load before kb's MFMAs
        const short* pn = (kb < 3) ? (pd + (kb + 1) * 32) : (pq + (kb - 3) * 32);
        u = *(const bf16x8*)pn;
      }
      const char* abase = (const char*)w1t + cc * 512 + ((((kb * 4 + q) ^ (cc & 7))) << 4);
      #pragma unroll
      for (int nt = 0; nt < 8; ++nt) {
        bf16x8 af = *(const bf16x8*)(abase + nt * 8192);
        acc1[nt] = MFMA16(af, bfr, acc1[nt]);
      }
    }

    // epilogue 1: LN over n=128, GELU, pack to bf16 hreg (acc1 dies here)
    bf16x8 hreg[4];
    {
      float s = 0.f, ss = 0.f;
      #pragma unroll
      for (int nt = 0; nt < 8; ++nt)
        #pragma unroll
        for (int j = 0; j < 4; ++j) { float v = acc1[nt][j]; s += v; ss += v * v; }
      s  += __shfl_xor(s, 16);  s  += __shfl_xor(s, 32);
      ss += __shfl_xor(ss, 16); ss += __shfl_xor(ss, 32);
      float mu   = s * 0.0078125f;
      float var  = ss * 0.0078125f - mu * mu;
      var = (var > 0.f) ? var : 0.f;
      float rstd = __builtin_amdgcn_rsqf(var + 1e-5f);

      #pragma unroll
      for (int h = 0; h < 4; ++h) {
        f32x4 glo = *(const f32x4*)(g1s + (2 * h) * 16 + q * 4);
        f32x4 elo = *(const f32x4*)(e1s + (2 * h) * 16 + q * 4);
        f32x4 ghi = *(const f32x4*)(g1s + (2 * h + 1) * 16 + q * 4);
        f32x4 ehi = *(const f32x4*)(e1s + (2 * h + 1) * 16 + q * 4);
        f32x4 a, b;
        #pragma unroll
        for (int j = 0; j < 4; ++j) {
          a[j] = gelu_fast(__builtin_fmaf((acc1[2 * h][j] - mu) * rstd, glo[j], elo[j]));
          b[j] = gelu_fast(__builtin_fmaf((acc1[2 * h + 1][j] - mu) * rstd, ghi[j], ehi[j]));
        }
        hreg[h] = pack8(a, b);
      }
    }

    // ===== layer 2: [128]->[64], B operand = hreg (pi-permuted, lane-local),
    // A fragments streamed from global (L1-hot), fenced to cap reg pressure =====
    f32x4 acc2[4];
    #pragma unroll
    for (int t = 0; t < 4; ++t)
      acc2[t] = *(const f32x4*)(b2s + t * 16 + q * 4);

    #pragma unroll
    for (int kb2 = 0; kb2 < 4; ++kb2) {
      bf16x8 hb = hreg[kb2];
      const int ch = ((kb2 * 4 + q) ^ (cc & 7));      // swizzled chunk
      #pragma unroll
      for (int t = 0; t < 4; ++t) {
        bf16x8 af = *(const bf16x8*)(w2p + t * 2048 + ch * 8);
        acc2[t] = MFMA16(af, hb, acc2[t]);
      }
      __builtin_amdgcn_sched_barrier(0);   // cap in-flight W2 loads at 4 (16 regs)
    }

    // epilogue 2: LN over n=64, GELU, dot with W3, +b3, store
    {
      float s = 0.f, ss = 0.f;
      #pragma unroll
      for (int t = 0; t < 4; ++t)
        #pragma unroll
        for (int j = 0; j < 4; ++j) { float v = acc2[t][j]; s += v; ss += v * v; }
      s  += __shfl_xor(s, 16);  s  += __shfl_xor(s, 32);
      ss += __shfl_xor(ss, 16); ss += __shfl_xor(ss, 32);
      float mu   = s * 0.015625f;
      float var  = ss * 0.015625f - mu * mu;
      var = (var > 0.f) ? var : 0.f;
      float rstd = __builtin_amdgcn_rsqf(var + 1e-5f);

      float dot = 0.f;
      #pragma unroll
      for (int t = 0; t < 4; ++t) {
        f32x4 gv = *(const f32x4*)(g2s + t * 16 + q * 4);
        f32x4 ev = *(const f32x4*)(e2s + t * 16 + q * 4);
        f32x4 wv = *(const f32x4*)(w3s + t * 16 + q * 4);
        #pragma unroll
        for (int j = 0; j < 4; ++j) {
          float zz = __builtin_fmaf((acc2[t][j] - mu) * rstd, gv[j], ev[j]);
          dot = __builtin_fmaf(gelu_fast(zz), wv[j], dot);
        }
      }
      dot += __shfl_xor(dot, 16); dot += __shfl_xor(dot, 32);
      if (q == 0 && r < E) out[r] = dot + b3s[0];
    }
  }
}

extern "C" void kernel_launch(void* const* d_in, const int* in_sizes, int n_in,
                              void* d_out, int out_size, void* d_ws, size_t ws_size,
                              hipStream_t stream) {
  const float* drug = (const float*)d_in[0];
  const float* dis  = (const float*)d_in[1];
  const int*   src  = (const int*)d_in[2];
  const int*   dst  = (const int*)d_in[3];
  const float* W1   = (const float*)d_in[4];
  const float* b1   = (const float*)d_in[5];
  const float* g1   = (const float*)d_in[6];
  const float* be1  = (const float*)d_in[7];
  const float* W2   = (const float*)d_in[8];
  const float* b2   = (const float*)d_in[9];
  const float* g2   = (const float*)d_in[10];
  const float* be2  = (const float*)d_in[11];
  const float* W3   = (const float*)d_in[12];
  const float* b3   = (const float*)d_in[13];
  float* out = (float*)d_out;

  const int E      = in_sizes[2];
  const int ndrug8 = in_sizes[0] / 8;      // drug floats / 8 (10000*128/8 = 160000)
  const int ndis8  = in_sizes[1] / 8;
  const int ntiles = (E + 127) / 128;      // 128-edge tiles (8 waves x 16 edges)

  short* w1i   = (short*)d_ws;             // 32768 shorts
  short* w2i   = w1i + 32768;              // 8192 shorts
  short* drugb = w2i + 8192;               // in_sizes[0] shorts (1.28M)
  short* disb  = drugb + (size_t)ndrug8 * 8;  // in_sizes[1] shorts (~5.2 MB ws total)

  (void)hipFuncSetAttribute((const void*)mlp_fused,
                            hipFuncAttributeMaxDynamicSharedMemorySize, SMEM_BYTES);

  prep_weights<<<dim3(160), dim3(256), 0, stream>>>(W1, W2, w1i, w2i);
  prep_feats<<<dim3((ndrug8 + 255) / 256), dim3(256), 0, stream>>>(drug, drugb, ndrug8);
  prep_feats<<<dim3((ndis8 + 255) / 256), dim3(256), 0, stream>>>(dis, disb, ndis8);

  int grid = 512;
  if (ntiles < grid) grid = ntiles;
  mlp_fused<<<dim3(grid), dim3(512), SMEM_BYTES, stream>>>(
      drugb, disb, src, dst, w1i, w2i, b1, g1, be1, b2, g2, be2, W3, b3, out, E, ntiles);
}